// Round 2
// baseline (879.285 us; speedup 1.0000x reference)
//
#include <hip/hip_runtime.h>

#define D_IN 256
#define D_HID 512
#define D_OUT 256

// ---------------------------------------------------------------------------
// Phase 1: per-node degree (with self-loop weight 1) + edge-count histogram
// ---------------------------------------------------------------------------
__global__ __launch_bounds__(256) void init_nodes(float* __restrict__ deg,
                                                  int* __restrict__ cnt, int N) {
    int i = blockIdx.x * 256 + threadIdx.x;
    if (i < N) { deg[i] = 1.0f; cnt[i] = 0; }   // deg starts at self-loop weight
}

__global__ __launch_bounds__(256) void edge_deg(const int* __restrict__ ei,
                                                const float* __restrict__ ew,
                                                float* __restrict__ deg,
                                                int* __restrict__ cnt, int E) {
    int e = blockIdx.x * 256 + threadIdx.x;
    if (e < E) {
        int c = ei[E + e];               // edge_index[1][e] = target
        atomicAdd(&deg[c], ew[e]);
        atomicAdd(&cnt[c], 1);
    }
}

__global__ __launch_bounds__(256) void make_dinv(float* __restrict__ deg, int N) {
    int i = blockIdx.x * 256 + threadIdx.x;
    if (i < N) deg[i] = rsqrtf(deg[i]);  // deg >= 1 always (self-loop)
}

// ---------------------------------------------------------------------------
// Phase 2: single-block exclusive scan of cnt -> offs.
// Chunked: each of 1024 threads owns ceil(N/1024) contiguous elements;
// thread-local sum -> shfl_up wave scan -> 16-wave LDS combine -> local
// prefix writeback. 2 barriers total (old version: ~1000).
// ---------------------------------------------------------------------------
__global__ __launch_bounds__(1024) void scan_excl(const int* __restrict__ cnt,
                                                  int* __restrict__ offs, int N) {
    __shared__ int wsum[16];
    int t = threadIdx.x;
    const int CH = (N + 1023) / 1024;
    int base = t * CH;
    int s = 0;
    for (int j = 0; j < CH; ++j) {
        int idx = base + j;
        if (idx < N) s += cnt[idx];
    }
    // inclusive scan across the 64-lane wave
    int lane = t & 63;
    int incl = s;
#pragma unroll
    for (int off = 1; off < 64; off <<= 1) {
        int v = __shfl_up(incl, off, 64);
        if (lane >= off) incl += v;
    }
    int wid = t >> 6;
    if (lane == 63) wsum[wid] = incl;
    __syncthreads();
    if (t < 16) {                        // threads 0..15 are all in wave 0
        int v = wsum[t];
#pragma unroll
        for (int off = 1; off < 16; off <<= 1) {
            int u = __shfl_up(v, off, 64);
            if (t >= off) v += u;
        }
        wsum[t] = v;                     // inclusive wave sums
    }
    __syncthreads();
    int waveoff = (wid == 0) ? 0 : wsum[wid - 1];
    int run = waveoff + incl - s;        // exclusive offset of this chunk
    for (int j = 0; j < CH; ++j) {
        int idx = base + j;
        if (idx < N) { offs[idx] = run; run += cnt[idx]; }
    }
}

// ---------------------------------------------------------------------------
// Phase 3: bin edges by target; pack (src, norm) into one 8B record.
// offs[i] is used as a running cursor; after this kernel offs[i] holds the
// INCLUSIVE prefix (end of node i's segment) -- exploited by gather_agg.
// ---------------------------------------------------------------------------
__global__ __launch_bounds__(256) void fill_edges(const int* __restrict__ ei,
                                                  const float* __restrict__ ew,
                                                  const float* __restrict__ dinv,
                                                  int* __restrict__ offs,
                                                  int2* __restrict__ epk, int E) {
    int e = blockIdx.x * 256 + threadIdx.x;
    if (e < E) {
        int r = ei[e];                    // source
        int c = ei[E + e];                // target
        float nm = dinv[r] * ew[e] * dinv[c];
        int pos = atomicAdd(&offs[c], 1);
        int2 p; p.x = r; p.y = __float_as_int(nm);
        epk[pos] = p;
    }
}

// ---------------------------------------------------------------------------
// Phase 4: gather-aggregate. One wave (64 lanes) per node; lane owns 4 floats
// of the 256-wide row (float4). agg[i] = dinv[i]^2 * x[i] + sum norm * x[src].
// ---------------------------------------------------------------------------
__global__ __launch_bounds__(64) void gather_agg(const float* __restrict__ x,
                                                 const int2* __restrict__ epk,
                                                 const int* __restrict__ offs,
                                                 const float* __restrict__ dinv,
                                                 float* __restrict__ agg, int N) {
    int i = blockIdx.x;
    int lane = threadIdx.x;
    int start = (i == 0) ? 0 : offs[i - 1];
    int end = offs[i];
    float di = dinv[i];
    float sw = di * di;
    float4 acc = *(const float4*)(x + (size_t)i * D_IN + lane * 4);
    acc.x *= sw; acc.y *= sw; acc.z *= sw; acc.w *= sw;
#pragma unroll 2
    for (int e = start; e < end; ++e) {
        int2 p = epk[e];
        float nm = __int_as_float(p.y);
        const float4 v = *(const float4*)(x + (size_t)p.x * D_IN + lane * 4);
        acc.x = fmaf(nm, v.x, acc.x);
        acc.y = fmaf(nm, v.y, acc.y);
        acc.z = fmaf(nm, v.z, acc.z);
        acc.w = fmaf(nm, v.w, acc.w);
    }
    *(float4*)(agg + (size_t)i * D_IN + lane * 4) = acc;
}

// ---------------------------------------------------------------------------
// Phase 5/6: f32 tiled GEMM, C[M,NO] = A[M,K] * B[NO,K]^T + bias (opt. relu).
// BM=BN=128, BK=32, 256 threads, 8x8 micro-tile per thread. VALU-bound
// (64 v_fmac_f32 vs 4 ds_read_b128 per k-step). No f32 MFMA on CDNA4.
// NOTE (next round, once baseline counters land): replace with split-bf16
// MFMA (a_hi*b_hi + a_hi*b_lo + a_lo*b_hi via mfma_f32_16x16x32_bf16),
// ~1e-4 rel err, ~3x expected on these two dispatches.
// ---------------------------------------------------------------------------
template <bool RELU>
__global__ __launch_bounds__(256) void gemm_nt(const float* __restrict__ A,
                                               const float* __restrict__ B,
                                               const float* __restrict__ bias,
                                               float* __restrict__ C,
                                               int M, int K, int NO) {
    const int BK = 32;
    __shared__ float As[BK][132];   // [k][m], padded
    __shared__ float Bs[BK][132];   // [k][n], padded
    int t = threadIdx.x;
    int m0 = blockIdx.y * 128;
    int n0 = blockIdx.x * 128;
    int tx = t & 15, ty = t >> 4;
    int ra = t >> 1;                 // 0..127: row within tile
    int kq = (t & 1) * 16;           // which half of the 32-wide k slab

    float acc[8][8];
#pragma unroll
    for (int i = 0; i < 8; ++i)
#pragma unroll
        for (int j = 0; j < 8; ++j) acc[i][j] = 0.0f;

    int mrow = m0 + ra; if (mrow > M - 1) mrow = M - 1;   // clamp tail loads
    const float* Aptr = A + (size_t)mrow * K + kq;
    const float* Bptr = B + (size_t)(n0 + ra) * K + kq;

    for (int k0 = 0; k0 < K; k0 += BK) {
#pragma unroll
        for (int j = 0; j < 4; ++j) {
            int kk = kq + j * 4;
            float4 va = *(const float4*)(Aptr + k0 + j * 4);
            As[kk + 0][ra] = va.x; As[kk + 1][ra] = va.y;
            As[kk + 2][ra] = va.z; As[kk + 3][ra] = va.w;
            float4 vb = *(const float4*)(Bptr + k0 + j * 4);
            Bs[kk + 0][ra] = vb.x; Bs[kk + 1][ra] = vb.y;
            Bs[kk + 2][ra] = vb.z; Bs[kk + 3][ra] = vb.w;
        }
        __syncthreads();
#pragma unroll
        for (int k = 0; k < BK; ++k) {
            float a[8], b[8];
            *(float4*)&a[0] = *(const float4*)&As[k][ty * 8];
            *(float4*)&a[4] = *(const float4*)&As[k][ty * 8 + 4];
            *(float4*)&b[0] = *(const float4*)&Bs[k][tx * 8];
            *(float4*)&b[4] = *(const float4*)&Bs[k][tx * 8 + 4];
#pragma unroll
            for (int i = 0; i < 8; ++i)
#pragma unroll
                for (int j = 0; j < 8; ++j)
                    acc[i][j] = fmaf(a[i], b[j], acc[i][j]);
        }
        __syncthreads();
    }

    float bv[8];
    *(float4*)&bv[0] = *(const float4*)(bias + n0 + tx * 8);
    *(float4*)&bv[4] = *(const float4*)(bias + n0 + tx * 8 + 4);
#pragma unroll
    for (int i = 0; i < 8; ++i) {
        int m = m0 + ty * 8 + i;
        if (m < M) {
            float out[8];
#pragma unroll
            for (int j = 0; j < 8; ++j) {
                float v = acc[i][j] + bv[j];
                out[j] = RELU ? fmaxf(v, 0.0f) : v;
            }
            *(float4*)(C + (size_t)m * NO + n0 + tx * 8) = *(float4*)&out[0];
            *(float4*)(C + (size_t)m * NO + n0 + tx * 8 + 4) = *(float4*)&out[4];
        }
    }
}

// ---------------------------------------------------------------------------
extern "C" void kernel_launch(void* const* d_in, const int* in_sizes, int n_in,
                              void* d_out, int out_size, void* d_ws, size_t ws_size,
                              hipStream_t stream) {
    const float* x  = (const float*)d_in[0];
    const int*   ei = (const int*)d_in[1];    // edge_index [2,E] as int32
    const float* ew = (const float*)d_in[2];
    const float* W1 = (const float*)d_in[3];  // [512,256]
    const float* b1 = (const float*)d_in[4];
    const float* W2 = (const float*)d_in[5];  // [256,512]
    const float* b2 = (const float*)d_in[6];

    const int N = in_sizes[0] / D_IN;         // 50000
    const int E = in_sizes[2];                // 1000000

    // workspace layout (~8.8 MB)
    char* ws = (char*)d_ws;
    size_t off = 0;
    auto take = [&](size_t bytes) -> char* {
        char* p = ws + off;
        off += (bytes + 255) & ~(size_t)255;
        return p;
    };
    float* deg  = (float*)take((size_t)N * 4);   // becomes dinv in-place
    int*   cnt  = (int*)take((size_t)N * 4);
    int*   offs = (int*)take((size_t)N * 4);
    int2*  epk  = (int2*)take((size_t)E * 8);

    // agg lives in the logits region of d_out (GEMM1 consumes it fully before
    // GEMM2 overwrites it with logits). h is the second output region.
    float* agg    = (float*)d_out;                       // [N,256]
    float* h      = (float*)d_out + (size_t)N * D_IN;    // [N,512]
    float* logits = (float*)d_out;                       // [N,256]

    int nb = (N + 255) / 256;
    int eb = (E + 255) / 256;

    init_nodes<<<nb, 256, 0, stream>>>(deg, cnt, N);
    edge_deg<<<eb, 256, 0, stream>>>(ei, ew, deg, cnt, E);
    make_dinv<<<nb, 256, 0, stream>>>(deg, N);
    scan_excl<<<1, 1024, 0, stream>>>(cnt, offs, N);
    fill_edges<<<eb, 256, 0, stream>>>(ei, ew, deg, offs, epk, E);
    gather_agg<<<N, 64, 0, stream>>>(x, epk, offs, deg, agg, N);

    dim3 g1(D_HID / 128, (N + 127) / 128);
    gemm_nt<true><<<g1, 256, 0, stream>>>(agg, W1, b1, h, N, D_IN, D_HID);
    dim3 g2(D_OUT / 128, (N + 127) / 128);
    gemm_nt<false><<<g2, 256, 0, stream>>>(h, W2, b2, logits, N, D_HID, D_OUT);
}

// Round 11
// 707.326 us; speedup vs baseline: 1.2431x; 1.2431x over previous
//
#include <hip/hip_runtime.h>

typedef __bf16 bf16;
typedef __attribute__((ext_vector_type(8))) __bf16 bf16x8;
typedef __attribute__((ext_vector_type(4))) __bf16 bf16x4;
typedef __attribute__((ext_vector_type(4))) float f32x4;

#define D_IN 256
#define D_HID 512
#define D_OUT 256

// async 16B global->LDS copy (dest is wave-uniform base + lane*16)
__device__ inline void async_copy16(void* lds_dst, const void* g_src) {
    __builtin_amdgcn_global_load_lds(
        (const __attribute__((address_space(1))) unsigned int*)g_src,
        (__attribute__((address_space(3))) unsigned int*)lds_dst, 16, 0, 0);
}

// Dekker-style split: f = hi + lo (both bf16), residual <= 2^-16 relative.
// Returned by value: ext_vector elements can't bind to non-const refs.
struct bfpair { bf16 h, l; };
__device__ inline bfpair split2(float f) {
    bf16 hh = (bf16)f;
    return { hh, (bf16)(f - (float)hh) };
}

// ---------------------------------------------------------------------------
// Phase 1: per-node degree (with self-loop weight 1) + edge-count histogram
// ---------------------------------------------------------------------------
__global__ __launch_bounds__(256) void init_nodes(float* __restrict__ deg,
                                                  int* __restrict__ cnt, int N) {
    int i = blockIdx.x * 256 + threadIdx.x;
    if (i < N) { deg[i] = 1.0f; cnt[i] = 0; }
}

__global__ __launch_bounds__(256) void edge_deg(const int* __restrict__ ei,
                                                const float* __restrict__ ew,
                                                float* __restrict__ deg,
                                                int* __restrict__ cnt, int E) {
    int e = blockIdx.x * 256 + threadIdx.x;
    if (e < E) {
        int c = ei[E + e];
        atomicAdd(&deg[c], ew[e]);
        atomicAdd(&cnt[c], 1);
    }
}

__global__ __launch_bounds__(256) void make_dinv(float* __restrict__ deg, int N) {
    int i = blockIdx.x * 256 + threadIdx.x;
    if (i < N) deg[i] = rsqrtf(deg[i]);
}

// ---------------------------------------------------------------------------
// Phase 2: single-block exclusive scan (chunked, 2 barriers)
// ---------------------------------------------------------------------------
__global__ __launch_bounds__(1024) void scan_excl(const int* __restrict__ cnt,
                                                  int* __restrict__ offs, int N) {
    __shared__ int wsum[16];
    int t = threadIdx.x;
    const int CH = (N + 1023) / 1024;
    int base = t * CH;
    int s = 0;
    for (int j = 0; j < CH; ++j) {
        int idx = base + j;
        if (idx < N) s += cnt[idx];
    }
    int lane = t & 63;
    int incl = s;
#pragma unroll
    for (int off = 1; off < 64; off <<= 1) {
        int v = __shfl_up(incl, off, 64);
        if (lane >= off) incl += v;
    }
    int wid = t >> 6;
    if (lane == 63) wsum[wid] = incl;
    __syncthreads();
    if (t < 16) {
        int v = wsum[t];
#pragma unroll
        for (int off = 1; off < 16; off <<= 1) {
            int u = __shfl_up(v, off, 64);
            if (t >= off) v += u;
        }
        wsum[t] = v;
    }
    __syncthreads();
    int waveoff = (wid == 0) ? 0 : wsum[wid - 1];
    int run = waveoff + incl - s;
    for (int j = 0; j < CH; ++j) {
        int idx = base + j;
        if (idx < N) { offs[idx] = run; run += cnt[idx]; }
    }
}

// ---------------------------------------------------------------------------
// Phase 3: bin edges by target; pack (src, norm)
// ---------------------------------------------------------------------------
__global__ __launch_bounds__(256) void fill_edges(const int* __restrict__ ei,
                                                  const float* __restrict__ ew,
                                                  const float* __restrict__ dinv,
                                                  int* __restrict__ offs,
                                                  int2* __restrict__ epk, int E) {
    int e = blockIdx.x * 256 + threadIdx.x;
    if (e < E) {
        int r = ei[e];
        int c = ei[E + e];
        float nm = dinv[r] * ew[e] * dinv[c];
        int pos = atomicAdd(&offs[c], 1);
        int2 p; p.x = r; p.y = __float_as_int(nm);
        epk[pos] = p;
    }
}

// ---------------------------------------------------------------------------
// Phase 4: gather-aggregate; output written as SPLIT bf16 pair (hi, lo) that
// feeds GEMM1's MFMA path directly. Pair lives in d_out's logits region.
// ---------------------------------------------------------------------------
__global__ __launch_bounds__(64) void gather_agg(const float* __restrict__ x,
                                                 const int2* __restrict__ epk,
                                                 const int* __restrict__ offs,
                                                 const float* __restrict__ dinv,
                                                 bf16* __restrict__ Ahi,
                                                 bf16* __restrict__ Alo, int N) {
    int i = blockIdx.x;
    int lane = threadIdx.x;
    int start = (i == 0) ? 0 : offs[i - 1];
    int end = offs[i];
    float di = dinv[i];
    float sw = di * di;
    float4 acc = *(const float4*)(x + (size_t)i * D_IN + lane * 4);
    acc.x *= sw; acc.y *= sw; acc.z *= sw; acc.w *= sw;
#pragma unroll 2
    for (int e = start; e < end; ++e) {
        int2 p = epk[e];
        float nm = __int_as_float(p.y);
        const float4 v = *(const float4*)(x + (size_t)p.x * D_IN + lane * 4);
        acc.x = fmaf(nm, v.x, acc.x);
        acc.y = fmaf(nm, v.y, acc.y);
        acc.z = fmaf(nm, v.z, acc.z);
        acc.w = fmaf(nm, v.w, acc.w);
    }
    bf16x4 hv, lv;
    bfpair p0 = split2(acc.x); hv[0] = p0.h; lv[0] = p0.l;
    bfpair p1 = split2(acc.y); hv[1] = p1.h; lv[1] = p1.l;
    bfpair p2 = split2(acc.z); hv[2] = p2.h; lv[2] = p2.l;
    bfpair p3 = split2(acc.w); hv[3] = p3.h; lv[3] = p3.l;
    size_t o = (size_t)i * D_IN + lane * 4;
    *(bf16x4*)(Ahi + o) = hv;
    *(bf16x4*)(Alo + o) = lv;
}

// ---------------------------------------------------------------------------
// Split an f32 array into bf16 (hi, lo) pair. n must be a multiple of 4.
// ---------------------------------------------------------------------------
__global__ __launch_bounds__(256) void split_pair(const float* __restrict__ src,
                                                  bf16* __restrict__ hi,
                                                  bf16* __restrict__ lo, int n) {
    int i = (blockIdx.x * 256 + threadIdx.x) * 4;
    if (i < n) {
        float4 v = *(const float4*)(src + i);
        bf16x4 hv, lv;
        bfpair p0 = split2(v.x); hv[0] = p0.h; lv[0] = p0.l;
        bfpair p1 = split2(v.y); hv[1] = p1.h; lv[1] = p1.l;
        bfpair p2 = split2(v.z); hv[2] = p2.h; lv[2] = p2.l;
        bfpair p3 = split2(v.w); hv[3] = p3.h; lv[3] = p3.l;
        *(bf16x4*)(hi + i) = hv;
        *(bf16x4*)(lo + i) = lv;
    }
}

// ---------------------------------------------------------------------------
// Split-bf16 MFMA GEMM: C[M,NO] = A[M,K] * B[NO,K]^T + bias, opt relu.
// A,B given as bf16 (hi,lo) pairs; 3-term MFMA: hi*hi + hi*lo + lo*hi.
// BM=BN=128, BK=32, 256 threads (4 waves 2x2, 64x64 per wave, 4x4 frags of
// 16x16x32). LDS tiles [kg][row][8 bf16] = fragment-contiguous (lane l reads
// row=l&15, kg=l>>4 -> 16 consecutive 16B slots per quarter-wave, no bank
// conflicts). A staged via global_load_lds (CVT_A=false) or on-the-fly f32
// split (CVT_A=true, for the h->GEMM2 path where A only exists as f32).
// ---------------------------------------------------------------------------
template <bool RELU, bool CVT_A>
__global__ __launch_bounds__(256) void gemm_mfma(
    const bf16* __restrict__ Ahi, const bf16* __restrict__ Alo,
    const float* __restrict__ Af32,
    const bf16* __restrict__ Bhi, const bf16* __restrict__ Blo,
    const float* __restrict__ bias, float* __restrict__ C,
    int M, int K, int NO) {
    __shared__ bf16 sAhi[4 * 128 * 8];   // 8 KB each, 32 KB total
    __shared__ bf16 sAlo[4 * 128 * 8];
    __shared__ bf16 sBhi[4 * 128 * 8];
    __shared__ bf16 sBlo[4 * 128 * 8];

    const int t = threadIdx.x;
    const int l = t & 63;
    const int w = t >> 6;
    const int m0 = blockIdx.y * 128;
    const int n0 = blockIdx.x * 128;
    const int wm = w >> 1, wn = w & 1;

    // --- staging geometry ---
    // gl_lds chunks: c = j*256 + w*64 + l ; kg = c>>7 ; row = c&127
    size_t boff[2];
    int dchunk[2];
    size_t aoff[2];
#pragma unroll
    for (int j = 0; j < 2; ++j) {
        int c = j * 256 + w * 64 + l;
        int kg = c >> 7, row = c & 127;
        boff[j] = (size_t)(n0 + row) * K + kg * 8;
        dchunk[j] = (j * 256 + w * 64) * 8;   // wave-uniform dest (bf16 elems)
        int rg = m0 + row; if (rg > M - 1) rg = M - 1;
        aoff[j] = (size_t)rg * K + kg * 8;
    }
    // CVT_A: thread t loads 16 f32 of row (t>>1), k-half (t&1)*16
    const int rowA = t >> 1;
    const int khA = (t & 1) * 16;
    const int kgA = (t & 1) * 2;
    const float* pA = nullptr;
    if (CVT_A) {
        int rg = m0 + rowA; if (rg > M - 1) rg = M - 1;
        pA = Af32 + (size_t)rg * K + khA;
    }

    f32x4 acc[4][4];
#pragma unroll
    for (int mi = 0; mi < 4; ++mi)
#pragma unroll
        for (int ni = 0; ni < 4; ++ni) acc[mi][ni] = (f32x4){0.f, 0.f, 0.f, 0.f};

    const int fl = l & 15;
    const int fk = l >> 4;
    const int abase = (fk * 128 + wm * 64 + fl) * 8;
    const int bbase = (fk * 128 + wn * 64 + fl) * 8;

    for (int k0 = 0; k0 < K; k0 += 32) {
        bf16x8 h0, h1, l0v, l1v;
        if (CVT_A) {
            // global f32 loads + convert BEFORE the barrier (overlaps compute)
            float4 va0 = *(const float4*)(pA + k0);
            float4 va1 = *(const float4*)(pA + k0 + 4);
            float4 va2 = *(const float4*)(pA + k0 + 8);
            float4 va3 = *(const float4*)(pA + k0 + 12);
            bfpair q;
            q = split2(va0.x); h0[0] = q.h; l0v[0] = q.l;
            q = split2(va0.y); h0[1] = q.h; l0v[1] = q.l;
            q = split2(va0.z); h0[2] = q.h; l0v[2] = q.l;
            q = split2(va0.w); h0[3] = q.h; l0v[3] = q.l;
            q = split2(va1.x); h0[4] = q.h; l0v[4] = q.l;
            q = split2(va1.y); h0[5] = q.h; l0v[5] = q.l;
            q = split2(va1.z); h0[6] = q.h; l0v[6] = q.l;
            q = split2(va1.w); h0[7] = q.h; l0v[7] = q.l;
            q = split2(va2.x); h1[0] = q.h; l1v[0] = q.l;
            q = split2(va2.y); h1[1] = q.h; l1v[1] = q.l;
            q = split2(va2.z); h1[2] = q.h; l1v[2] = q.l;
            q = split2(va2.w); h1[3] = q.h; l1v[3] = q.l;
            q = split2(va3.x); h1[4] = q.h; l1v[4] = q.l;
            q = split2(va3.y); h1[5] = q.h; l1v[5] = q.l;
            q = split2(va3.z); h1[6] = q.h; l1v[6] = q.l;
            q = split2(va3.w); h1[7] = q.h; l1v[7] = q.l;
        }
        __syncthreads();   // previous compute done; safe to overwrite LDS
#pragma unroll
        for (int j = 0; j < 2; ++j) {
            async_copy16(sBhi + dchunk[j], Bhi + boff[j] + k0);
            async_copy16(sBlo + dchunk[j], Blo + boff[j] + k0);
            if (!CVT_A) {
                async_copy16(sAhi + dchunk[j], Ahi + aoff[j] + k0);
                async_copy16(sAlo + dchunk[j], Alo + aoff[j] + k0);
            }
        }
        if (CVT_A) {
            *(bf16x8*)(sAhi + (kgA * 128 + rowA) * 8) = h0;
            *(bf16x8*)(sAhi + ((kgA + 1) * 128 + rowA) * 8) = h1;
            *(bf16x8*)(sAlo + (kgA * 128 + rowA) * 8) = l0v;
            *(bf16x8*)(sAlo + ((kgA + 1) * 128 + rowA) * 8) = l1v;
        }
        __syncthreads();   // drains vmcnt (gl_lds) + lgkm (ds_write)

        bf16x8 ah[4], al[4], bh[4], bl[4];
#pragma unroll
        for (int mi = 0; mi < 4; ++mi) {
            ah[mi] = *(const bf16x8*)(sAhi + abase + mi * 16 * 8);
            al[mi] = *(const bf16x8*)(sAlo + abase + mi * 16 * 8);
        }
#pragma unroll
        for (int ni = 0; ni < 4; ++ni) {
            bh[ni] = *(const bf16x8*)(sBhi + bbase + ni * 16 * 8);
            bl[ni] = *(const bf16x8*)(sBlo + bbase + ni * 16 * 8);
        }
#pragma unroll
        for (int mi = 0; mi < 4; ++mi)
#pragma unroll
            for (int ni = 0; ni < 4; ++ni) {
                acc[mi][ni] = __builtin_amdgcn_mfma_f32_16x16x32_bf16(
                    ah[mi], bh[ni], acc[mi][ni], 0, 0, 0);
                acc[mi][ni] = __builtin_amdgcn_mfma_f32_16x16x32_bf16(
                    ah[mi], bl[ni], acc[mi][ni], 0, 0, 0);
                acc[mi][ni] = __builtin_amdgcn_mfma_f32_16x16x32_bf16(
                    al[mi], bh[ni], acc[mi][ni], 0, 0, 0);
            }
    }

    // epilogue: C/D layout col=l&15, row=(l>>4)*4+r  [verified m89]
    const int colb = n0 + wn * 64 + fl;
    const int rowb = m0 + wm * 64 + fk * 4;
    float bv[4];
#pragma unroll
    for (int ni = 0; ni < 4; ++ni) bv[ni] = bias[colb + ni * 16];
#pragma unroll
    for (int mi = 0; mi < 4; ++mi) {
#pragma unroll
        for (int r = 0; r < 4; ++r) {
            int row = rowb + mi * 16 + r;
            if (row < M) {
#pragma unroll
                for (int ni = 0; ni < 4; ++ni) {
                    float v = acc[mi][ni][r] + bv[ni];
                    if (RELU) v = fmaxf(v, 0.f);
                    C[(size_t)row * NO + colb + ni * 16] = v;
                }
            }
        }
    }
}

// ---------------------------------------------------------------------------
extern "C" void kernel_launch(void* const* d_in, const int* in_sizes, int n_in,
                              void* d_out, int out_size, void* d_ws, size_t ws_size,
                              hipStream_t stream) {
    const float* x  = (const float*)d_in[0];
    const int*   ei = (const int*)d_in[1];
    const float* ew = (const float*)d_in[2];
    const float* W1 = (const float*)d_in[3];  // [512,256]
    const float* b1 = (const float*)d_in[4];
    const float* W2 = (const float*)d_in[5];  // [256,512]
    const float* b2 = (const float*)d_in[6];

    const int N = in_sizes[0] / D_IN;         // 50000
    const int E = in_sizes[2];                // 1000000

    // workspace (~9.8 MB)
    char* ws = (char*)d_ws;
    size_t off = 0;
    auto take = [&](size_t bytes) -> char* {
        char* p = ws + off;
        off += (bytes + 255) & ~(size_t)255;
        return p;
    };
    float* deg   = (float*)take((size_t)N * 4);
    int*   cnt   = (int*)take((size_t)N * 4);
    int*   offs  = (int*)take((size_t)N * 4);
    int2*  epk   = (int2*)take((size_t)E * 8);
    bf16*  W1hi  = (bf16*)take((size_t)D_HID * D_IN * 2);
    bf16*  W1lo  = (bf16*)take((size_t)D_HID * D_IN * 2);
    bf16*  W2hi  = (bf16*)take((size_t)D_OUT * D_HID * 2);
    bf16*  W2lo  = (bf16*)take((size_t)D_OUT * D_HID * 2);

    // agg split-pair lives in d_out's logits region (51.2 MB = exactly
    // N*D_IN*2 bf16 arrays). GEMM1 consumes it fully before GEMM2's epilogue
    // overwrites the region with logits (kernel boundary = barrier).
    bf16*  Ahi    = (bf16*)d_out;
    bf16*  Alo    = Ahi + (size_t)N * D_IN;
    float* h      = (float*)d_out + (size_t)N * D_IN;    // [N,512] output
    float* logits = (float*)d_out;                       // [N,256] output

    int nb = (N + 255) / 256;
    int eb = (E + 255) / 256;

    init_nodes<<<nb, 256, 0, stream>>>(deg, cnt, N);
    edge_deg<<<eb, 256, 0, stream>>>(ei, ew, deg, cnt, E);
    make_dinv<<<nb, 256, 0, stream>>>(deg, N);
    scan_excl<<<1, 1024, 0, stream>>>(cnt, offs, N);
    fill_edges<<<eb, 256, 0, stream>>>(ei, ew, deg, offs, epk, E);
    gather_agg<<<N, 64, 0, stream>>>(x, epk, offs, deg, Ahi, Alo, N);

    split_pair<<<(D_HID * D_IN) / 1024, 256, 0, stream>>>(W1, W1hi, W1lo, D_HID * D_IN);
    split_pair<<<(D_OUT * D_HID) / 1024, 256, 0, stream>>>(W2, W2hi, W2lo, D_OUT * D_HID);

    dim3 g1(D_HID / 128, (N + 127) / 128);
    gemm_mfma<true, false><<<g1, 256, 0, stream>>>(Ahi, Alo, nullptr,
                                                   W1hi, W1lo, b1, h,
                                                   N, D_IN, D_HID);
    dim3 g2(D_OUT / 128, (N + 127) / 128);
    gemm_mfma<false, true><<<g2, 256, 0, stream>>>(nullptr, nullptr, h,
                                                   W2hi, W2lo, b2, logits,
                                                   N, D_HID, D_OUT);
}